// Round 19
// baseline (323.626 us; speedup 1.0000x reference)
//
#include <hip/hip_runtime.h>
#include <hip/hip_bf16.h>

typedef _Float16 h16;
typedef _Float16 h16x8 __attribute__((ext_vector_type(8)));
typedef float f32x4 __attribute__((ext_vector_type(4)));

#define DEVI static __device__ __forceinline__
// swizzled byte offset within a [128][128] h16 tile (256 B rows)
#define PSW(row, colbyte) ((((row) * 256) + (colbyte)) ^ (((row) & 7) << 4))

constexpr int NN = 2048;     // sequence length
constexpr int DIM = 512;
constexpr int NH = 8;
constexpr int DH = 64;
constexpr int BH = 16;       // B * H
constexpr float FSCALE = 0.125f;  // DH^-0.5

DEVI f32x4 mfma16(h16x8 a, h16x8 b, f32x4 c) {
  return __builtin_amdgcn_mfma_f32_16x16x32_f16(a, b, c, 0, 0, 0);
}

DEVI void glds16(const void* g, void* l) {
  __builtin_amdgcn_global_load_lds(
      (const __attribute__((address_space(1))) unsigned int*)g,
      (__attribute__((address_space(3))) unsigned int*)l, 16, 0, 0);
}

DEVI void tri_decode(int p, int& a, int& b) {
  a = (int)((sqrtf(8.f * p + 1.f) - 1.f) * 0.5f);
  while ((a + 1) * (a + 2) / 2 <= p) ++a;
  while (a * (a + 1) / 2 > p) --a;
  b = p - a * (a + 1) / 2;
}

// ---------------- pack kernels ----------------

__global__ __launch_bounds__(256) void k_pack_x(const float* __restrict__ x, h16* __restrict__ xh) {
  int i = (blockIdx.x * 256 + threadIdx.x) * 4;
  float4 v = *(const float4*)(x + i);
  union { h16 h[4]; uint2 u; } pk;
  pk.h[0] = (h16)v.x; pk.h[1] = (h16)v.y; pk.h[2] = (h16)v.z; pk.h[3] = (h16)v.w;
  *(uint2*)(xh + i) = pk.u;
}

struct WPtrs { const float* w[7]; };

// transpose+cast each 512x512 weight: wt[o][k] = W[k][o]
__global__ __launch_bounds__(256) void k_pack_w(WPtrs wp, h16* __restrict__ wt) {
  const float* W = wp.w[blockIdx.z];
  h16* out = wt + (size_t)blockIdx.z * DIM * DIM;
  __shared__ h16 t[64][65];
  int k0 = blockIdx.x * 64, o0 = blockIdx.y * 64;
  int c = threadIdx.x & 63, r4 = threadIdx.x >> 6;
#pragma unroll
  for (int rr = 0; rr < 64; rr += 4) {
    int r = rr + r4;
    t[r][c] = (h16)W[(size_t)(k0 + r) * DIM + o0 + c];
  }
  __syncthreads();
#pragma unroll
  for (int rr = 0; rr < 64; rr += 4) {
    int r = rr + r4;
    out[(size_t)(o0 + r) * DIM + k0 + c] = t[c][r];
  }
}

// ---------------- fused QKV projection ----------------
__global__ __launch_bounds__(256) void k_proj(const h16* __restrict__ xh, const h16* __restrict__ wt,
                                              h16* __restrict__ qkv, h16* __restrict__ vcT) {
  __shared__ h16 pool[128 * 136];
  h16* Al = pool;
  h16* Bl = pool + 128 * 64;
  int m0 = blockIdx.x * 128, o0 = blockIdx.y * 128;
  int lane = threadIdx.x & 63, wv = threadIdx.x >> 6;
  int wy = wv >> 1, wx = wv & 1;
  int srow = 32 * wv;
  int lr = lane >> 3, lc = 8 * (lane & 7);
  f32x4 acc[4][4] = {};
  for (int ks0 = 0; ks0 < DIM; ks0 += 64) {
#pragma unroll
    for (int inst = 0; inst < 4; inst++) {
      int r = srow + 8 * inst;
      glds16(xh + (size_t)(m0 + r + lr) * DIM + ks0 + lc, Al + r * 64);
      glds16(wt + (size_t)(o0 + r + lr) * DIM + ks0 + lc, Bl + r * 64);
    }
    __syncthreads();
#pragma unroll
    for (int ks = 0; ks < 2; ks++) {
      h16x8 af[4], bfv[4];
      int co = 32 * ks + 8 * (lane >> 4);
#pragma unroll
      for (int i = 0; i < 4; i++) af[i] = *(const h16x8*)(Al + (64 * wy + 16 * i + (lane & 15)) * 64 + co);
#pragma unroll
      for (int j = 0; j < 4; j++) bfv[j] = *(const h16x8*)(Bl + (64 * wx + 16 * j + (lane & 15)) * 64 + co);
#pragma unroll
      for (int i = 0; i < 4; i++)
#pragma unroll
        for (int j = 0; j < 4; j++) acc[i][j] = mfma16(af[i], bfv[j], acc[i][j]);
    }
    __syncthreads();
  }
  int widx = o0 >> 9;
  float scl = (widx == 0 || widx == 3) ? FSCALE : 1.0f;
  h16 (*Clds)[136] = (h16(*)[136])pool;
#pragma unroll
  for (int i = 0; i < 4; i++)
#pragma unroll
    for (int j = 0; j < 4; j++)
#pragma unroll
      for (int r = 0; r < 4; r++) {
        int rloc = 64 * wy + 16 * i + (lane >> 4) * 4 + r;
        int cloc = 64 * wx + 16 * j + (lane & 15);
        Clds[rloc][cloc] = (h16)(acc[i][j][r] * scl);
      }
  __syncthreads();
  int t = threadIdx.x;
  {
    int rloc = t >> 1, half = t & 1;
    int gi = m0 + rloc;
    int b = gi >> 11, n = gi & 2047;
    int og = o0 + 64 * half;
    int h = (og >> 6) & 7;
    h16* dst = qkv + (((size_t)widx * BH + b * NH + h) * NN + n) * DH;
#pragma unroll
    for (int e = 0; e < 8; e++)
      *(h16x8*)(dst + 8 * e) = *(const h16x8*)&Clds[rloc][64 * half + 8 * e];
  }
  if (widx == 5) {
    int c = t & 127, rq = t >> 7;
    int og = o0 + c;
    int h = (og >> 6) & 7, d = og & 63;
    int b = m0 >> 11, nb = (m0 & 2047) + rq * 64;
    h16* dst = vcT + ((size_t)(b * NH + h) * DH + d) * NN + nb;
#pragma unroll
    for (int g = 0; g < 8; g++) {
      h16x8 w;
#pragma unroll
      for (int e = 0; e < 8; e++) w[e] = Clds[rq * 64 + 8 * g + e][c];
      *(h16x8*)(dst + 8 * g) = w;
    }
  }
}

// ---------------- term1 & sigmoid matrices (merged, triangular tile-packed) ----------------
// 32KB pool (unpadded swizzled C tile) -> 5 blocks/CU
__global__ __launch_bounds__(256, 4) void k_termsig(const h16* __restrict__ qkv,
                                                    h16* __restrict__ term, h16* __restrict__ sig, int bh0) {
  int pidx = blockIdx.x;
  int lz = blockIdx.z, bh = bh0 + lz;
  int a, bq;
  tri_decode(pidx, a, bq);
  int lane = threadIdx.x & 63, wv = threadIdx.x >> 6;
  int wy = wv >> 1, wx = wv & 1;
  int l15 = lane & 15, q4 = lane >> 4;
  int lr = lane >> 3, lchunk = lane & 7;
  __shared__ h16 pool[128 * 128];
  h16* Al = pool;
  h16* Bl = pool + 128 * 64;
  size_t slot = ((size_t)lz * 136 + (size_t)a * (a + 1) / 2 + bq) * 16384;

  for (int ph = 0; ph < 2; ph++) {
    bool is_sig = (ph == 1);
    int rt = is_sig ? bq : a;
    int jt = is_sig ? a : bq;
    const h16* A  = qkv + ((size_t)(is_sig ? 0 : 3) * BH + bh) * NN * DH;
    const h16* Bv = qkv + ((size_t)(is_sig ? 1 : 2) * BH + bh) * NN * DH;
    h16* out = (is_sig ? sig : term) + slot;
#pragma unroll
    for (int inst = 0; inst < 4; inst++) {
      int rbase = 32 * wv + 8 * inst;
      int row = rbase + lr;
      int sc_ = (lchunk ^ (row & 7)) * 8;
      glds16(A + (size_t)(rt * 128 + row) * DH + sc_, Al + rbase * 64);
      glds16(Bv + (size_t)(jt * 128 + row) * DH + sc_, Bl + rbase * 64);
    }
    __syncthreads();
    f32x4 acc[4][4] = {};
#pragma unroll
    for (int ks = 0; ks < 2; ks++) {
      int co = 32 * ks + 8 * q4;
      h16x8 af[4], bfv[4];
#pragma unroll
      for (int i = 0; i < 4; i++) {
        int row = 64 * wy + 16 * i + l15;
        af[i] = *(const h16x8*)((const char*)Al + ((row * 128 + co * 2) ^ ((row & 7) << 4)));
      }
#pragma unroll
      for (int j = 0; j < 4; j++) {
        int row = 64 * wx + 16 * j + l15;
        bfv[j] = *(const h16x8*)((const char*)Bl + ((row * 128 + co * 2) ^ ((row & 7) << 4)));
      }
#pragma unroll
      for (int i = 0; i < 4; i++)
#pragma unroll
        for (int j = 0; j < 4; j++) acc[i][j] = mfma16(af[i], bfv[j], acc[i][j]);
    }
    __syncthreads();
#pragma unroll
    for (int i = 0; i < 4; i++)
#pragma unroll
      for (int j = 0; j < 4; j++)
#pragma unroll
        for (int r = 0; r < 4; r++) {
          int rloc = 64 * wy + 16 * i + q4 * 4 + r;
          int cloc = 64 * wx + 16 * j + l15;
          int gr = rt * 128 + rloc;
          int gj = jt * 128 + cloc;
          float v = acc[i][j][r];
          float o;
          if (!is_sig) o = (gj <= gr) ? v : 0.f;
          else         o = (gj > gr) ? 1.f / (1.f + __expf(-v)) : 0.f;
          *(h16*)((char*)pool + PSW(rloc, cloc * 2)) = (h16)o;
        }
    __syncthreads();
    int t = threadIdx.x;
    int rloc = t >> 1, half = t & 1;
    h16* dst = out + (size_t)rloc * 128 + 64 * half;
#pragma unroll
    for (int e = 0; e < 8; e++)
      *(h16x8*)(dst + 8 * e) = *(const h16x8*)((const char*)pool + PSW(rloc, (64 * half + 8 * e) * 2));
    __syncthreads();  // tile fully consumed before next phase's stage overwrites pool
  }
}

// ---------------- scores + fused PV (packed term/sig, unshifted exp) ----------------
// 32KB pool (unpadded swizzled P tile) -> 5 blocks/CU
__global__ __launch_bounds__(256, 4) void k_scores(const h16* __restrict__ qkv,
                                                   const h16* __restrict__ term, const h16* __restrict__ sig,
                                                   const h16* __restrict__ vcT,
                                                   h16* __restrict__ Ot,
                                                   float* __restrict__ psum, int bh0) {
  __shared__ h16 pool[128 * 128];  // loop: Al+Bl (32KB); epilogue: swizzled P [128][128]
  h16* Al = pool;
  h16* Bl = pool + 128 * 64;
  int nwg = gridDim.x;
  int q = nwg >> 3, rmd = nwg & 7;
  int xcd = blockIdx.x & 7, idx = blockIdx.x >> 3;
  int wg = (xcd < rmd) ? xcd * (q + 1) + idx : rmd * (q + 1) + (xcd - rmd) * q + idx;
  int lz = wg / 136, r = wg % 136;
  int It = 15, base = 0;               // descending: longest K-loops first
  while (r - base >= It + 1) { base += It + 1; --It; }
  int Kt = r - base;                   // Kt <= It
  int bh = bh0 + lz;
  int i0 = It * 128, k0 = Kt * 128;
  int triIt = It * (It + 1) / 2;
  const h16* termP = term + (size_t)lz * 136 * 16384;
  const h16* sigP  = sig + (size_t)lz * 136 * 16384;
  int lane = threadIdx.x & 63, wv = threadIdx.x >> 6;
  int wy = wv >> 1, wx = wv & 1;
  int l15 = lane & 15, q4 = lane >> 4;
  int lr = lane >> 3, lchunk = lane & 7;
  f32x4 acc[4][4] = {};
  for (int js = k0; js < i0 + 128; js += 64) {
    int jt = js >> 7, joff = js & 64;
    const h16* At = termP + (size_t)(triIt + jt) * 16384;            // term tile (It, jt)
    const h16* Bt = sigP + (size_t)(jt * (jt + 1) / 2 + Kt) * 16384; // sig tile (Kt, jt)
#pragma unroll
    for (int inst = 0; inst < 4; inst++) {
      int rbase = 32 * wv + 8 * inst;
      int row = rbase + lr;
      int sc_ = (lchunk ^ (row & 7)) * 8;
      glds16(At + (size_t)row * 128 + joff + sc_, Al + rbase * 64);
      glds16(Bt + (size_t)row * 128 + joff + sc_, Bl + rbase * 64);
    }
    __syncthreads();
#pragma unroll
    for (int ks = 0; ks < 2; ks++) {
      int co = 32 * ks + 8 * q4;
      h16x8 af[4], bfv[4];
#pragma unroll
      for (int i = 0; i < 4; i++) {
        int row = 64 * wy + 16 * i + l15;
        af[i] = *(const h16x8*)((const char*)Al + ((row * 128 + co * 2) ^ ((row & 7) << 4)));
      }
#pragma unroll
      for (int j = 0; j < 4; j++) {
        int row = 64 * wx + 16 * j + l15;
        bfv[j] = *(const h16x8*)((const char*)Bl + ((row * 128 + co * 2) ^ ((row & 7) << 4)));
      }
#pragma unroll
      for (int i = 0; i < 4; i++)
#pragma unroll
        for (int j = 0; j < 4; j++) acc[i][j] = mfma16(af[i], bfv[j], acc[i][j]);
    }
    __syncthreads();
  }
  // acc = -silu(S_u)
#pragma unroll
  for (int i = 0; i < 4; i++)
#pragma unroll
    for (int j = 0; j < 4; j++)
#pragma unroll
      for (int rr = 0; rr < 4; rr++) {
        float xv = acc[i][j][rr];
        acc[i][j][rr] = -xv / (1.f + __expf(-xv));
      }
  // acc += Qc_s . Kc^T
  const h16* Q  = qkv + ((size_t)3 * BH + bh) * NN * DH;
  const h16* Kc = qkv + ((size_t)4 * BH + bh) * NN * DH;
#pragma unroll
  for (int d2 = 0; d2 < 2; d2++) {
    int kb = 32 * d2 + 8 * q4;
    h16x8 af[4], bfv[4];
#pragma unroll
    for (int i = 0; i < 4; i++)
      af[i] = *(const h16x8*)(Q + (size_t)(i0 + 64 * wy + 16 * i + l15) * DH + kb);
#pragma unroll
    for (int j = 0; j < 4; j++)
      bfv[j] = *(const h16x8*)(Kc + (size_t)(k0 + 64 * wx + 16 * j + l15) * DH + kb);
#pragma unroll
    for (int i = 0; i < 4; i++)
#pragma unroll
      for (int j = 0; j < 4; j++) acc[i][j] = mfma16(af[i], bfv[j], acc[i][j]);
  }
  // --- P = exp(masked s) into swizzled [128][128] LDS; mask only on diagonal tiles ---
  if (It == Kt) {
#pragma unroll
    for (int i = 0; i < 4; i++)
#pragma unroll
      for (int j = 0; j < 4; j++)
#pragma unroll
        for (int rr = 0; rr < 4; rr++) {
          int rloc = 64 * wy + 16 * i + q4 * 4 + rr;
          int cloc = 64 * wx + 16 * j + l15;
          float pv = (cloc <= rloc) ? __expf(acc[i][j][rr]) : 0.f;
          *(h16*)((char*)pool + PSW(rloc, cloc * 2)) = (h16)pv;
        }
  } else {
#pragma unroll
    for (int i = 0; i < 4; i++)
#pragma unroll
      for (int j = 0; j < 4; j++)
#pragma unroll
        for (int rr = 0; rr < 4; rr++) {
          int rloc = 64 * wy + 16 * i + q4 * 4 + rr;
          int cloc = 64 * wx + 16 * j + l15;
          *(h16*)((char*)pool + PSW(rloc, cloc * 2)) = (h16)__expf(acc[i][j][rr]);
        }
  }
  __syncthreads();
  // --- row partial sums ---
  int t = threadIdx.x;
  {
    int rloc = t >> 1, half = t & 1;
    float ls = 0.f;
#pragma unroll
    for (int e = 0; e < 8; e++) {
      h16x8 v8 = *(const h16x8*)((const char*)pool + PSW(rloc, (64 * half + 8 * e) * 2));
#pragma unroll
      for (int qe = 0; qe < 8; qe++) ls += (float)v8[qe];
    }
    ls += __shfl_xor(ls, 1);
    if (half == 0) psum[((size_t)lz * 16 + Kt) * NN + i0 + rloc] = ls;
  }
  // --- fused PV: O_t = P @ Vc[Kt-tile]  (each wave: 64 rows x 32 d) ---
  const h16* VT = vcT + (size_t)bh * DH * NN;  // [d][n]
  f32x4 acc2[4][2] = {};
#pragma unroll
  for (int ks = 0; ks < 4; ks++) {
    int co = 32 * ks + 8 * q4;
    h16x8 bf2[2];
#pragma unroll
    for (int n = 0; n < 2; n++)
      bf2[n] = *(const h16x8*)(VT + (size_t)(32 * wx + 16 * n + l15) * NN + k0 + co);
#pragma unroll
    for (int m = 0; m < 4; m++) {
      int prow = 64 * wy + 16 * m + l15;
      h16x8 af2 = *(const h16x8*)((const char*)pool + PSW(prow, co * 2));
#pragma unroll
      for (int n = 0; n < 2; n++) acc2[m][n] = mfma16(af2, bf2[n], acc2[m][n]);
    }
  }
  h16* ob = Ot + ((size_t)lz * 136 + triIt + Kt) * (128 * 64);
#pragma unroll
  for (int m = 0; m < 4; m++)
#pragma unroll
    for (int n = 0; n < 2; n++)
#pragma unroll
      for (int rr = 0; rr < 4; rr++) {
        int row = 64 * wy + 16 * m + 4 * q4 + rr;
        int col = 32 * wx + 16 * n + l15;
        ob[row * 64 + col] = (h16)acc2[m][n][rr];
      }
}

// ---------------- fused merge + output projection (CH==16 path, single group/block) ----------------
__global__ __launch_bounds__(256) void k_pvout(const h16* __restrict__ Ot,
                                               const float* __restrict__ psum,
                                               const h16* __restrict__ Wt,
                                               float* __restrict__ out) {
  int m0 = blockIdx.x * 16;       // global row (b*2048 + n)
  int b = m0 >> 11;
  int i0 = m0 & 2047;
  int It = i0 >> 7;
  int ntk = It + 1, triIt = It * (It + 1) / 2;
  int rbase = i0 & 127;
  __shared__ h16 attnL[16][520];  // pad 520: 2-way-free GEMM reads
  int t = threadIdx.x;
  {
    int r = t >> 4, cseg = t & 15;
    int col0 = cseg * 32;
    int h = col0 >> 6;
    int bh = b * 8 + h;
    int coff = col0 & 63;
    const float* pl = psum + (size_t)bh * 16 * NN + i0 + r;
    float L = 0.f;
    for (int k = 0; k < ntk; k++) L += pl[(size_t)k * NN];
    float invL = 1.f / L;
    float acc[32] = {};
    const h16* obase = Ot + ((size_t)bh * 136 + triIt) * 8192 + (size_t)(rbase + r) * 64 + coff;
    for (int k = 0; k < ntk; k++) {
      const h16* ob = obase + (size_t)k * 8192;
#pragma unroll
      for (int e = 0; e < 4; e++) {
        h16x8 v = *(const h16x8*)(ob + 8 * e);
#pragma unroll
        for (int qe = 0; qe < 8; qe++) acc[8 * e + qe] += (float)v[qe];
      }
    }
#pragma unroll
    for (int e = 0; e < 4; e++) {
      h16x8 o;
#pragma unroll
      for (int qe = 0; qe < 8; qe++) o[qe] = (h16)(acc[8 * e + qe] * invL);
      *(h16x8*)&attnL[r][col0 + 8 * e] = o;
    }
  }
  __syncthreads();
  // GEMM: out[m0..m0+15][:] = attnL @ Wt^T; wave wv covers out cols wv*128..+127
  int lane = t & 63, wv = t >> 6;
  int l15 = lane & 15, q4 = lane >> 4;
  f32x4 acc2[2][4] = {};
  for (int k0 = 0; k0 < DIM; k0 += 32) {
    h16x8 af = *(const h16x8*)&attnL[l15][k0 + 8 * q4];
#pragma unroll
    for (int c = 0; c < 2; c++)
#pragma unroll
      for (int tt = 0; tt < 4; tt++) {
        h16x8 bf = *(const h16x8*)(Wt + (size_t)(wv * 128 + c * 64 + tt * 16 + l15) * DIM + k0 + 8 * q4);
        acc2[c][tt] = mfma16(af, bf, acc2[c][tt]);
      }
  }
#pragma unroll
  for (int c = 0; c < 2; c++)
#pragma unroll
    for (int tt = 0; tt < 4; tt++)
#pragma unroll
      for (int rr = 0; rr < 4; rr++)
        out[(size_t)(m0 + 4 * q4 + rr) * DIM + wv * 128 + c * 64 + tt * 16 + l15] = acc2[c][tt][rr];
}

// ---------------- fallback: merge partial O tiles -> attn (CH<16 path) ----------------
__global__ __launch_bounds__(256) void k_pvm(const h16* __restrict__ Ot,
                                             const float* __restrict__ psum,
                                             h16* __restrict__ attn, int bh0) {
  int It = blockIdx.x, lz = blockIdx.y, bh = bh0 + lz;
  int t = threadIdx.x;
  int rloc = t >> 1, dh = (t & 1) * 32;
  int i = It * 128 + rloc;
  int ntk = It + 1;
  int triIt = It * (It + 1) / 2;
  const float* pl = psum + (size_t)lz * 16 * NN + i;
  float L = 0.f;
  for (int k = 0; k < ntk; k++) L += pl[(size_t)k * NN];
  float invL = 1.f / L;
  float acc[32] = {};
  for (int k = 0; k < ntk; k++) {
    const h16* ob = Ot + ((size_t)lz * 136 + triIt + k) * (128 * 64) + (size_t)rloc * 64 + dh;
#pragma unroll
    for (int e = 0; e < 4; e++) {
      h16x8 v = *(const h16x8*)(ob + 8 * e);
#pragma unroll
      for (int qe = 0; qe < 8; qe++) acc[8 * e + qe] += (float)v[qe];
    }
  }
  int hh = bh & 7, b = bh >> 3;
  h16* dst = attn + ((size_t)b * NN + i) * DIM + hh * DH + dh;
#pragma unroll
  for (int g = 0; g < 4; g++) {
    h16x8 o;
#pragma unroll
    for (int qe = 0; qe < 8; qe++) o[qe] = (h16)(acc[g * 8 + qe] * invL);
    *(h16x8*)(dst + 8 * g) = o;
  }
}

// ---------------- fallback: output projection (fp32 out) ----------------
__global__ __launch_bounds__(256) void k_outproj(const h16* __restrict__ attn, const h16* __restrict__ Wt,
                                                 float* __restrict__ out) {
  int m0 = blockIdx.x * 64, o0 = blockIdx.y * 64;
  int lane = threadIdx.x & 63, wv = threadIdx.x >> 6;
  int kb = 8 * (lane >> 4);
  f32x4 acc[4] = {};
  const h16* ap = attn + (size_t)(m0 + 16 * wv + (lane & 15)) * DIM + kb;
  const h16* bp = Wt + (size_t)(o0 + (lane & 15)) * DIM + kb;
  for (int k0 = 0; k0 < DIM; k0 += 32) {
    h16x8 af = *(const h16x8*)(ap + k0);
#pragma unroll
    for (int t = 0; t < 4; t++) {
      h16x8 bfv = *(const h16x8*)(bp + (size_t)(16 * t) * DIM + k0);
      acc[t] = mfma16(af, bfv, acc[t]);
    }
  }
  int ri = m0 + 16 * wv + (lane >> 4) * 4;
  int c0 = o0 + (lane & 15);
#pragma unroll
  for (int t = 0; t < 4; t++)
#pragma unroll
    for (int r = 0; r < 4; r++) out[(size_t)(ri + r) * DIM + c0 + 16 * t] = acc[t][r];
}

// ---------------- launch ----------------

extern "C" void kernel_launch(void* const* d_in, const int* in_sizes, int n_in,
                              void* d_out, int out_size, void* d_ws, size_t ws_size,
                              hipStream_t stream) {
  const float* x = (const float*)d_in[0];
  WPtrs wp;
  for (int i = 0; i < 7; i++) wp.w[i] = (const float*)d_in[1 + i];

  char* p = (char*)d_ws;
  auto alloc = [&](size_t bytes) {
    void* r = (void*)p;
    p += (bytes + 255) & ~(size_t)255;
    return r;
  };
  h16* xh   = (h16*)alloc((size_t)4096 * DIM * 2);            // 4 MB
  h16* wt   = (h16*)alloc((size_t)7 * DIM * DIM * 2);         // 3.5 MB
  h16* qkv  = (h16*)alloc((size_t)6 * BH * NN * DH * 2);      // 24 MB
  h16* vcT  = (h16*)alloc((size_t)BH * DH * NN * 2);          // 4 MB
  h16* attn = (h16*)alloc((size_t)4096 * DIM * 2);            // 4 MB (fallback path only)
  size_t used = (size_t)(p - (char*)d_ws);
  size_t ts_bh = (size_t)136 * 16384 * 2;                     // 4.46 MB packed term/sig each
  size_t ot_bh = (size_t)136 * 128 * 64 * 2;                  // 2.23 MB partial-O (h16) per bh
  size_t pp_bh = (size_t)16 * NN * 4;                         // 128 KB partials per bh
  size_t avail = ws_size > used ? ws_size - used : 0;
  int CH = 16;
  while (CH > 1 && (size_t)CH * (ts_bh * 2 + ot_bh + pp_bh) > avail) CH >>= 1;
  h16* term   = (h16*)alloc((size_t)CH * ts_bh);
  h16* sig    = (h16*)alloc((size_t)CH * ts_bh);
  h16* Ot     = (h16*)alloc((size_t)CH * ot_bh);
  float* psum = (float*)alloc((size_t)CH * pp_bh);
  const h16* wout = wt + (size_t)6 * DIM * DIM;

  k_pack_x<<<dim3(2048), dim3(256), 0, stream>>>(x, xh);
  k_pack_w<<<dim3(8, 8, 7), dim3(256), 0, stream>>>(wp, wt);
  k_proj<<<dim3(32, 24), dim3(256), 0, stream>>>(xh, wt, qkv, vcT);

  if (CH == 16) {
    k_termsig<<<dim3(136, 1, 16), dim3(256), 0, stream>>>(qkv, term, sig, 0);
    k_scores<<<dim3(136 * 16), dim3(256), 0, stream>>>(qkv, term, sig, vcT, Ot, psum, 0);
    k_pvout<<<dim3(256), dim3(256), 0, stream>>>(Ot, psum, wout, (float*)d_out);
  } else {
    for (int c0 = 0; c0 < BH; c0 += CH) {
      k_termsig<<<dim3(136, 1, CH), dim3(256), 0, stream>>>(qkv, term, sig, c0);
      k_scores<<<dim3(136 * CH), dim3(256), 0, stream>>>(qkv, term, sig, vcT, Ot, psum, c0);
      k_pvm<<<dim3(16, CH), dim3(256), 0, stream>>>(Ot, psum, attn, c0);
    }
    k_outproj<<<dim3(64, 8), dim3(256), 0, stream>>>(attn, wout, (float*)d_out);
  }
}

// Round 20
// 244.863 us; speedup vs baseline: 1.3217x; 1.3217x over previous
//
#include <hip/hip_runtime.h>
#include <hip/hip_bf16.h>

typedef _Float16 h16;
typedef _Float16 h16x8 __attribute__((ext_vector_type(8)));
typedef float f32x4 __attribute__((ext_vector_type(4)));

#define DEVI static __device__ __forceinline__

constexpr int NN = 2048;     // sequence length
constexpr int DIM = 512;
constexpr int NH = 8;
constexpr int DH = 64;
constexpr int BH = 16;       // B * H
constexpr float FSCALE = 0.125f;  // DH^-0.5

DEVI f32x4 mfma16(h16x8 a, h16x8 b, f32x4 c) {
  return __builtin_amdgcn_mfma_f32_16x16x32_f16(a, b, c, 0, 0, 0);
}

DEVI void glds16(const void* g, void* l) {
  __builtin_amdgcn_global_load_lds(
      (const __attribute__((address_space(1))) unsigned int*)g,
      (__attribute__((address_space(3))) unsigned int*)l, 16, 0, 0);
}

DEVI void tri_decode(int p, int& a, int& b) {
  a = (int)((sqrtf(8.f * p + 1.f) - 1.f) * 0.5f);
  while ((a + 1) * (a + 2) / 2 <= p) ++a;
  while (a * (a + 1) / 2 > p) --a;
  b = p - a * (a + 1) / 2;
}

// ---------------- pack kernels ----------------

__global__ __launch_bounds__(256) void k_pack_x(const float* __restrict__ x, h16* __restrict__ xh) {
  int i = (blockIdx.x * 256 + threadIdx.x) * 4;
  float4 v = *(const float4*)(x + i);
  union { h16 h[4]; uint2 u; } pk;
  pk.h[0] = (h16)v.x; pk.h[1] = (h16)v.y; pk.h[2] = (h16)v.z; pk.h[3] = (h16)v.w;
  *(uint2*)(xh + i) = pk.u;
}

struct WPtrs { const float* w[7]; };

// transpose+cast each 512x512 weight: wt[o][k] = W[k][o]
__global__ __launch_bounds__(256) void k_pack_w(WPtrs wp, h16* __restrict__ wt) {
  const float* W = wp.w[blockIdx.z];
  h16* out = wt + (size_t)blockIdx.z * DIM * DIM;
  __shared__ h16 t[64][65];
  int k0 = blockIdx.x * 64, o0 = blockIdx.y * 64;
  int c = threadIdx.x & 63, r4 = threadIdx.x >> 6;
#pragma unroll
  for (int rr = 0; rr < 64; rr += 4) {
    int r = rr + r4;
    t[r][c] = (h16)W[(size_t)(k0 + r) * DIM + o0 + c];
  }
  __syncthreads();
#pragma unroll
  for (int rr = 0; rr < 64; rr += 4) {
    int r = rr + r4;
    out[(size_t)(o0 + r) * DIM + k0 + c] = t[c][r];
  }
}

// ---------------- fused QKV projection ----------------
__global__ __launch_bounds__(256) void k_proj(const h16* __restrict__ xh, const h16* __restrict__ wt,
                                              h16* __restrict__ qkv, h16* __restrict__ vcT) {
  __shared__ h16 pool[128 * 136];
  h16* Al = pool;
  h16* Bl = pool + 128 * 64;
  int m0 = blockIdx.x * 128, o0 = blockIdx.y * 128;
  int lane = threadIdx.x & 63, wv = threadIdx.x >> 6;
  int wy = wv >> 1, wx = wv & 1;
  int srow = 32 * wv;
  int lr = lane >> 3, lc = 8 * (lane & 7);
  f32x4 acc[4][4] = {};
  for (int ks0 = 0; ks0 < DIM; ks0 += 64) {
#pragma unroll
    for (int inst = 0; inst < 4; inst++) {
      int r = srow + 8 * inst;
      glds16(xh + (size_t)(m0 + r + lr) * DIM + ks0 + lc, Al + r * 64);
      glds16(wt + (size_t)(o0 + r + lr) * DIM + ks0 + lc, Bl + r * 64);
    }
    __syncthreads();
#pragma unroll
    for (int ks = 0; ks < 2; ks++) {
      h16x8 af[4], bfv[4];
      int co = 32 * ks + 8 * (lane >> 4);
#pragma unroll
      for (int i = 0; i < 4; i++) af[i] = *(const h16x8*)(Al + (64 * wy + 16 * i + (lane & 15)) * 64 + co);
#pragma unroll
      for (int j = 0; j < 4; j++) bfv[j] = *(const h16x8*)(Bl + (64 * wx + 16 * j + (lane & 15)) * 64 + co);
#pragma unroll
      for (int i = 0; i < 4; i++)
#pragma unroll
        for (int j = 0; j < 4; j++) acc[i][j] = mfma16(af[i], bfv[j], acc[i][j]);
    }
    __syncthreads();
  }
  int widx = o0 >> 9;
  float scl = (widx == 0 || widx == 3) ? FSCALE : 1.0f;
  h16 (*Clds)[136] = (h16(*)[136])pool;
#pragma unroll
  for (int i = 0; i < 4; i++)
#pragma unroll
    for (int j = 0; j < 4; j++)
#pragma unroll
      for (int r = 0; r < 4; r++) {
        int rloc = 64 * wy + 16 * i + (lane >> 4) * 4 + r;
        int cloc = 64 * wx + 16 * j + (lane & 15);
        Clds[rloc][cloc] = (h16)(acc[i][j][r] * scl);
      }
  __syncthreads();
  int t = threadIdx.x;
  {
    int rloc = t >> 1, half = t & 1;
    int gi = m0 + rloc;
    int b = gi >> 11, n = gi & 2047;
    int og = o0 + 64 * half;
    int h = (og >> 6) & 7;
    h16* dst = qkv + (((size_t)widx * BH + b * NH + h) * NN + n) * DH;
#pragma unroll
    for (int e = 0; e < 8; e++)
      *(h16x8*)(dst + 8 * e) = *(const h16x8*)&Clds[rloc][64 * half + 8 * e];
  }
  if (widx == 5) {
    int c = t & 127, rq = t >> 7;
    int og = o0 + c;
    int h = (og >> 6) & 7, d = og & 63;
    int b = m0 >> 11, nb = (m0 & 2047) + rq * 64;
    h16* dst = vcT + ((size_t)(b * NH + h) * DH + d) * NN + nb;
#pragma unroll
    for (int g = 0; g < 8; g++) {
      h16x8 w;
#pragma unroll
      for (int e = 0; e < 8; e++) w[e] = Clds[rq * 64 + 8 * g + e][c];
      *(h16x8*)(dst + 8 * g) = w;
    }
  }
}

// ---------------- term1 & sigmoid matrices (merged, triangular tile-packed) ----------------
__global__ __launch_bounds__(256, 4) void k_termsig(const h16* __restrict__ qkv,
                                                    h16* __restrict__ term, h16* __restrict__ sig, int bh0) {
  int pidx = blockIdx.x;
  int lz = blockIdx.z, bh = bh0 + lz;
  int a, bq;
  tri_decode(pidx, a, bq);
  int lane = threadIdx.x & 63, wv = threadIdx.x >> 6;
  int wy = wv >> 1, wx = wv & 1;
  int l15 = lane & 15, q4 = lane >> 4;
  int lr = lane >> 3, lchunk = lane & 7;
  __shared__ h16 pool[128 * 136];
  h16* Al = pool;
  h16* Bl = pool + 128 * 64;
  size_t slot = ((size_t)lz * 136 + (size_t)a * (a + 1) / 2 + bq) * 16384;

  for (int ph = 0; ph < 2; ph++) {
    bool is_sig = (ph == 1);
    int rt = is_sig ? bq : a;
    int jt = is_sig ? a : bq;
    const h16* A  = qkv + ((size_t)(is_sig ? 0 : 3) * BH + bh) * NN * DH;
    const h16* Bv = qkv + ((size_t)(is_sig ? 1 : 2) * BH + bh) * NN * DH;
    h16* out = (is_sig ? sig : term) + slot;
#pragma unroll
    for (int inst = 0; inst < 4; inst++) {
      int rbase = 32 * wv + 8 * inst;
      int row = rbase + lr;
      int sc_ = (lchunk ^ (row & 7)) * 8;
      glds16(A + (size_t)(rt * 128 + row) * DH + sc_, Al + rbase * 64);
      glds16(Bv + (size_t)(jt * 128 + row) * DH + sc_, Bl + rbase * 64);
    }
    __syncthreads();
    f32x4 acc[4][4] = {};
#pragma unroll
    for (int ks = 0; ks < 2; ks++) {
      int co = 32 * ks + 8 * q4;
      h16x8 af[4], bfv[4];
#pragma unroll
      for (int i = 0; i < 4; i++) {
        int row = 64 * wy + 16 * i + l15;
        af[i] = *(const h16x8*)((const char*)Al + ((row * 128 + co * 2) ^ ((row & 7) << 4)));
      }
#pragma unroll
      for (int j = 0; j < 4; j++) {
        int row = 64 * wx + 16 * j + l15;
        bfv[j] = *(const h16x8*)((const char*)Bl + ((row * 128 + co * 2) ^ ((row & 7) << 4)));
      }
#pragma unroll
      for (int i = 0; i < 4; i++)
#pragma unroll
        for (int j = 0; j < 4; j++) acc[i][j] = mfma16(af[i], bfv[j], acc[i][j]);
    }
    __syncthreads();
    h16 (*Clds)[136] = (h16(*)[136])pool;
#pragma unroll
    for (int i = 0; i < 4; i++)
#pragma unroll
      for (int j = 0; j < 4; j++)
#pragma unroll
        for (int r = 0; r < 4; r++) {
          int rloc = 64 * wy + 16 * i + q4 * 4 + r;
          int cloc = 64 * wx + 16 * j + l15;
          int gr = rt * 128 + rloc;
          int gj = jt * 128 + cloc;
          float v = acc[i][j][r];
          float o;
          if (!is_sig) o = (gj <= gr) ? v : 0.f;
          else         o = (gj > gr) ? 1.f / (1.f + __expf(-v)) : 0.f;
          Clds[rloc][cloc] = (h16)o;
        }
    __syncthreads();
    int t = threadIdx.x;
    int rloc = t >> 1, half = t & 1;
    h16* dst = out + (size_t)rloc * 128 + 64 * half;
#pragma unroll
    for (int e = 0; e < 8; e++)
      *(h16x8*)(dst + 8 * e) = *(const h16x8*)&Clds[rloc][64 * half + 8 * e];
    __syncthreads();  // Clds fully consumed before next phase's stage overwrites pool
  }
}

// ---------------- scores + fused PV (packed term/sig, unshifted exp) ----------------
__global__ __launch_bounds__(256, 4) void k_scores(const h16* __restrict__ qkv,
                                                   const h16* __restrict__ term, const h16* __restrict__ sig,
                                                   const h16* __restrict__ vcT,
                                                   h16* __restrict__ Ot,
                                                   float* __restrict__ psum, int bh0) {
  __shared__ h16 pool[128 * 136];  // loop: Al+Bl (32KB); epilogue: Clds[128][136] (P)
  h16* Al = pool;
  h16* Bl = pool + 128 * 64;
  int nwg = gridDim.x;
  int q = nwg >> 3, rmd = nwg & 7;
  int xcd = blockIdx.x & 7, idx = blockIdx.x >> 3;
  int wg = (xcd < rmd) ? xcd * (q + 1) + idx : rmd * (q + 1) + (xcd - rmd) * q + idx;
  int lz = wg / 136, r = wg % 136;
  int It = 15, base = 0;               // descending: longest K-loops first
  while (r - base >= It + 1) { base += It + 1; --It; }
  int Kt = r - base;                   // Kt <= It
  int bh = bh0 + lz;
  int i0 = It * 128, k0 = Kt * 128;
  int triIt = It * (It + 1) / 2;
  const h16* termP = term + (size_t)lz * 136 * 16384;
  const h16* sigP  = sig + (size_t)lz * 136 * 16384;
  int lane = threadIdx.x & 63, wv = threadIdx.x >> 6;
  int wy = wv >> 1, wx = wv & 1;
  int l15 = lane & 15, q4 = lane >> 4;
  int lr = lane >> 3, lchunk = lane & 7;
  f32x4 acc[4][4] = {};
  for (int js = k0; js < i0 + 128; js += 64) {
    int jt = js >> 7, joff = js & 64;
    const h16* At = termP + (size_t)(triIt + jt) * 16384;            // term tile (It, jt)
    const h16* Bt = sigP + (size_t)(jt * (jt + 1) / 2 + Kt) * 16384; // sig tile (Kt, jt)
#pragma unroll
    for (int inst = 0; inst < 4; inst++) {
      int rbase = 32 * wv + 8 * inst;
      int row = rbase + lr;
      int sc_ = (lchunk ^ (row & 7)) * 8;
      glds16(At + (size_t)row * 128 + joff + sc_, Al + rbase * 64);
      glds16(Bt + (size_t)row * 128 + joff + sc_, Bl + rbase * 64);
    }
    __syncthreads();
#pragma unroll
    for (int ks = 0; ks < 2; ks++) {
      int co = 32 * ks + 8 * q4;
      h16x8 af[4], bfv[4];
#pragma unroll
      for (int i = 0; i < 4; i++) {
        int row = 64 * wy + 16 * i + l15;
        af[i] = *(const h16x8*)((const char*)Al + ((row * 128 + co * 2) ^ ((row & 7) << 4)));
      }
#pragma unroll
      for (int j = 0; j < 4; j++) {
        int row = 64 * wx + 16 * j + l15;
        bfv[j] = *(const h16x8*)((const char*)Bl + ((row * 128 + co * 2) ^ ((row & 7) << 4)));
      }
#pragma unroll
      for (int i = 0; i < 4; i++)
#pragma unroll
        for (int j = 0; j < 4; j++) acc[i][j] = mfma16(af[i], bfv[j], acc[i][j]);
    }
    __syncthreads();
  }
  // acc = -silu(S_u)
#pragma unroll
  for (int i = 0; i < 4; i++)
#pragma unroll
    for (int j = 0; j < 4; j++)
#pragma unroll
      for (int rr = 0; rr < 4; rr++) {
        float xv = acc[i][j][rr];
        acc[i][j][rr] = -xv / (1.f + __expf(-xv));
      }
  // acc += Qc_s . Kc^T
  const h16* Q  = qkv + ((size_t)3 * BH + bh) * NN * DH;
  const h16* Kc = qkv + ((size_t)4 * BH + bh) * NN * DH;
#pragma unroll
  for (int d2 = 0; d2 < 2; d2++) {
    int kb = 32 * d2 + 8 * q4;
    h16x8 af[4], bfv[4];
#pragma unroll
    for (int i = 0; i < 4; i++)
      af[i] = *(const h16x8*)(Q + (size_t)(i0 + 64 * wy + 16 * i + l15) * DH + kb);
#pragma unroll
    for (int j = 0; j < 4; j++)
      bfv[j] = *(const h16x8*)(Kc + (size_t)(k0 + 64 * wx + 16 * j + l15) * DH + kb);
#pragma unroll
    for (int i = 0; i < 4; i++)
#pragma unroll
      for (int j = 0; j < 4; j++) acc[i][j] = mfma16(af[i], bfv[j], acc[i][j]);
  }
  // --- P = exp(masked s); mask only needed on diagonal tiles (It==Kt) ---
  h16 (*Clds)[136] = (h16(*)[136])pool;
  if (It == Kt) {
#pragma unroll
    for (int i = 0; i < 4; i++)
#pragma unroll
      for (int j = 0; j < 4; j++)
#pragma unroll
        for (int rr = 0; rr < 4; rr++) {
          int rloc = 64 * wy + 16 * i + q4 * 4 + rr;
          int cloc = 64 * wx + 16 * j + l15;
          float pv = (cloc <= rloc) ? __expf(acc[i][j][rr]) : 0.f;
          Clds[rloc][cloc] = (h16)pv;
        }
  } else {
#pragma unroll
    for (int i = 0; i < 4; i++)
#pragma unroll
      for (int j = 0; j < 4; j++)
#pragma unroll
        for (int rr = 0; rr < 4; rr++) {
          int rloc = 64 * wy + 16 * i + q4 * 4 + rr;
          int cloc = 64 * wx + 16 * j + l15;
          Clds[rloc][cloc] = (h16)__expf(acc[i][j][rr]);
        }
  }
  __syncthreads();
  // --- row partial sums ---
  int t = threadIdx.x;
  {
    int rloc = t >> 1, half = t & 1;
    float ls = 0.f;
#pragma unroll
    for (int e = 0; e < 8; e++) {
      h16x8 v8 = *(const h16x8*)&Clds[rloc][64 * half + 8 * e];
#pragma unroll
      for (int qe = 0; qe < 8; qe++) ls += (float)v8[qe];
    }
    ls += __shfl_xor(ls, 1);
    if (half == 0) psum[((size_t)lz * 16 + Kt) * NN + i0 + rloc] = ls;
  }
  // --- fused PV: O_t = P @ Vc[Kt-tile]  (each wave: 64 rows x 32 d) ---
  const h16* VT = vcT + (size_t)bh * DH * NN;  // [d][n]
  f32x4 acc2[4][2] = {};
#pragma unroll
  for (int ks = 0; ks < 4; ks++) {
    int co = 32 * ks + 8 * q4;
    h16x8 bf2[2];
#pragma unroll
    for (int n = 0; n < 2; n++)
      bf2[n] = *(const h16x8*)(VT + (size_t)(32 * wx + 16 * n + l15) * NN + k0 + co);
#pragma unroll
    for (int m = 0; m < 4; m++) {
      h16x8 af2 = *(const h16x8*)&Clds[64 * wy + 16 * m + l15][co];
#pragma unroll
      for (int n = 0; n < 2; n++) acc2[m][n] = mfma16(af2, bf2[n], acc2[m][n]);
    }
  }
  h16* ob = Ot + ((size_t)lz * 136 + triIt + Kt) * (128 * 64);
#pragma unroll
  for (int m = 0; m < 4; m++)
#pragma unroll
    for (int n = 0; n < 2; n++)
#pragma unroll
      for (int rr = 0; rr < 4; rr++) {
        int row = 64 * wy + 16 * m + 4 * q4 + rr;
        int col = 32 * wx + 16 * n + l15;
        ob[row * 64 + col] = (h16)acc2[m][n][rr];
      }
}

// ---------------- fused merge + output projection (CH==16 path, single group/block) ----------------
__global__ __launch_bounds__(256) void k_pvout(const h16* __restrict__ Ot,
                                               const float* __restrict__ psum,
                                               const h16* __restrict__ Wt,
                                               float* __restrict__ out) {
  int m0 = blockIdx.x * 16;       // global row (b*2048 + n)
  int b = m0 >> 11;
  int i0 = m0 & 2047;
  int It = i0 >> 7;
  int ntk = It + 1, triIt = It * (It + 1) / 2;
  int rbase = i0 & 127;
  __shared__ h16 attnL[16][520];  // pad 520: 2-way-free GEMM reads
  int t = threadIdx.x;
  {
    int r = t >> 4, cseg = t & 15;
    int col0 = cseg * 32;
    int h = col0 >> 6;
    int bh = b * 8 + h;
    int coff = col0 & 63;
    const float* pl = psum + (size_t)bh * 16 * NN + i0 + r;
    float L = 0.f;
    for (int k = 0; k < ntk; k++) L += pl[(size_t)k * NN];
    float invL = 1.f / L;
    float acc[32] = {};
    const h16* obase = Ot + ((size_t)bh * 136 + triIt) * 8192 + (size_t)(rbase + r) * 64 + coff;
    for (int k = 0; k < ntk; k++) {
      const h16* ob = obase + (size_t)k * 8192;
#pragma unroll
      for (int e = 0; e < 4; e++) {
        h16x8 v = *(const h16x8*)(ob + 8 * e);
#pragma unroll
        for (int qe = 0; qe < 8; qe++) acc[8 * e + qe] += (float)v[qe];
      }
    }
#pragma unroll
    for (int e = 0; e < 4; e++) {
      h16x8 o;
#pragma unroll
      for (int qe = 0; qe < 8; qe++) o[qe] = (h16)(acc[8 * e + qe] * invL);
      *(h16x8*)&attnL[r][col0 + 8 * e] = o;
    }
  }
  __syncthreads();
  // GEMM: out[m0..m0+15][:] = attnL @ Wt^T; wave wv covers out cols wv*128..+127
  int lane = t & 63, wv = t >> 6;
  int l15 = lane & 15, q4 = lane >> 4;
  f32x4 acc2[2][4] = {};
  for (int k0 = 0; k0 < DIM; k0 += 32) {
    h16x8 af = *(const h16x8*)&attnL[l15][k0 + 8 * q4];
#pragma unroll
    for (int c = 0; c < 2; c++)
#pragma unroll
      for (int tt = 0; tt < 4; tt++) {
        h16x8 bf = *(const h16x8*)(Wt + (size_t)(wv * 128 + c * 64 + tt * 16 + l15) * DIM + k0 + 8 * q4);
        acc2[c][tt] = mfma16(af, bf, acc2[c][tt]);
      }
  }
#pragma unroll
  for (int c = 0; c < 2; c++)
#pragma unroll
    for (int tt = 0; tt < 4; tt++)
#pragma unroll
      for (int rr = 0; rr < 4; rr++)
        out[(size_t)(m0 + 4 * q4 + rr) * DIM + wv * 128 + c * 64 + tt * 16 + l15] = acc2[c][tt][rr];
}

// ---------------- fallback: merge partial O tiles -> attn (CH<16 path) ----------------
__global__ __launch_bounds__(256) void k_pvm(const h16* __restrict__ Ot,
                                             const float* __restrict__ psum,
                                             h16* __restrict__ attn, int bh0) {
  int It = blockIdx.x, lz = blockIdx.y, bh = bh0 + lz;
  int t = threadIdx.x;
  int rloc = t >> 1, dh = (t & 1) * 32;
  int i = It * 128 + rloc;
  int ntk = It + 1;
  int triIt = It * (It + 1) / 2;
  const float* pl = psum + (size_t)lz * 16 * NN + i;
  float L = 0.f;
  for (int k = 0; k < ntk; k++) L += pl[(size_t)k * NN];
  float invL = 1.f / L;
  float acc[32] = {};
  for (int k = 0; k < ntk; k++) {
    const h16* ob = Ot + ((size_t)lz * 136 + triIt + k) * (128 * 64) + (size_t)rloc * 64 + dh;
#pragma unroll
    for (int e = 0; e < 4; e++) {
      h16x8 v = *(const h16x8*)(ob + 8 * e);
#pragma unroll
      for (int qe = 0; qe < 8; qe++) acc[8 * e + qe] += (float)v[qe];
    }
  }
  int hh = bh & 7, b = bh >> 3;
  h16* dst = attn + ((size_t)b * NN + i) * DIM + hh * DH + dh;
#pragma unroll
  for (int g = 0; g < 4; g++) {
    h16x8 o;
#pragma unroll
    for (int qe = 0; qe < 8; qe++) o[qe] = (h16)(acc[g * 8 + qe] * invL);
    *(h16x8*)(dst + 8 * g) = o;
  }
}

// ---------------- fallback: output projection (fp32 out) ----------------
__global__ __launch_bounds__(256) void k_outproj(const h16* __restrict__ attn, const h16* __restrict__ Wt,
                                                 float* __restrict__ out) {
  int m0 = blockIdx.x * 64, o0 = blockIdx.y * 64;
  int lane = threadIdx.x & 63, wv = threadIdx.x >> 6;
  int kb = 8 * (lane >> 4);
  f32x4 acc[4] = {};
  const h16* ap = attn + (size_t)(m0 + 16 * wv + (lane & 15)) * DIM + kb;
  const h16* bp = Wt + (size_t)(o0 + (lane & 15)) * DIM + kb;
  for (int k0 = 0; k0 < DIM; k0 += 32) {
    h16x8 af = *(const h16x8*)(ap + k0);
#pragma unroll
    for (int t = 0; t < 4; t++) {
      h16x8 bfv = *(const h16x8*)(bp + (size_t)(16 * t) * DIM + k0);
      acc[t] = mfma16(af, bfv, acc[t]);
    }
  }
  int ri = m0 + 16 * wv + (lane >> 4) * 4;
  int c0 = o0 + (lane & 15);
#pragma unroll
  for (int t = 0; t < 4; t++)
#pragma unroll
    for (int r = 0; r < 4; r++) out[(size_t)(ri + r) * DIM + c0 + 16 * t] = acc[t][r];
}

// ---------------- launch ----------------

extern "C" void kernel_launch(void* const* d_in, const int* in_sizes, int n_in,
                              void* d_out, int out_size, void* d_ws, size_t ws_size,
                              hipStream_t stream) {
  const float* x = (const float*)d_in[0];
  WPtrs wp;
  for (int i = 0; i < 7; i++) wp.w[i] = (const float*)d_in[1 + i];

  char* p = (char*)d_ws;
  auto alloc = [&](size_t bytes) {
    void* r = (void*)p;
    p += (bytes + 255) & ~(size_t)255;
    return r;
  };
  h16* xh   = (h16*)alloc((size_t)4096 * DIM * 2);            // 4 MB
  h16* wt   = (h16*)alloc((size_t)7 * DIM * DIM * 2);         // 3.5 MB
  h16* qkv  = (h16*)alloc((size_t)6 * BH * NN * DH * 2);      // 24 MB
  h16* vcT  = (h16*)alloc((size_t)BH * DH * NN * 2);          // 4 MB
  h16* attn = (h16*)alloc((size_t)4096 * DIM * 2);            // 4 MB (fallback path only)
  size_t used = (size_t)(p - (char*)d_ws);
  size_t ts_bh = (size_t)136 * 16384 * 2;                     // 4.46 MB packed term/sig each
  size_t ot_bh = (size_t)136 * 128 * 64 * 2;                  // 2.23 MB partial-O (h16) per bh
  size_t pp_bh = (size_t)16 * NN * 4;                         // 128 KB partials per bh
  size_t avail = ws_size > used ? ws_size - used : 0;
  int CH = 16;
  while (CH > 1 && (size_t)CH * (ts_bh * 2 + ot_bh + pp_bh) > avail) CH >>= 1;
  h16* term   = (h16*)alloc((size_t)CH * ts_bh);
  h16* sig    = (h16*)alloc((size_t)CH * ts_bh);
  h16* Ot     = (h16*)alloc((size_t)CH * ot_bh);
  float* psum = (float*)alloc((size_t)CH * pp_bh);
  const h16* wout = wt + (size_t)6 * DIM * DIM;

  k_pack_x<<<dim3(2048), dim3(256), 0, stream>>>(x, xh);
  k_pack_w<<<dim3(8, 8, 7), dim3(256), 0, stream>>>(wp, wt);
  k_proj<<<dim3(32, 24), dim3(256), 0, stream>>>(xh, wt, qkv, vcT);

  if (CH == 16) {
    k_termsig<<<dim3(136, 1, 16), dim3(256), 0, stream>>>(qkv, term, sig, 0);
    k_scores<<<dim3(136 * 16), dim3(256), 0, stream>>>(qkv, term, sig, vcT, Ot, psum, 0);
    k_pvout<<<dim3(256), dim3(256), 0, stream>>>(Ot, psum, wout, (float*)d_out);
  } else {
    for (int c0 = 0; c0 < BH; c0 += CH) {
      k_termsig<<<dim3(136, 1, CH), dim3(256), 0, stream>>>(qkv, term, sig, c0);
      k_scores<<<dim3(136 * CH), dim3(256), 0, stream>>>(qkv, term, sig, vcT, Ot, psum, c0);
      k_pvm<<<dim3(16, CH), dim3(256), 0, stream>>>(Ot, psum, attn, c0);
    }
    k_outproj<<<dim3(64, 8), dim3(256), 0, stream>>>(attn, wout, (float*)d_out);
  }
}

// Round 21
// 237.444 us; speedup vs baseline: 1.3630x; 1.0312x over previous
//
#include <hip/hip_runtime.h>
#include <hip/hip_bf16.h>

typedef _Float16 h16;
typedef _Float16 h16x8 __attribute__((ext_vector_type(8)));
typedef float f32x4 __attribute__((ext_vector_type(4)));

#define DEVI static __device__ __forceinline__

constexpr int NN = 2048;     // sequence length
constexpr int DIM = 512;
constexpr int NH = 8;
constexpr int DH = 64;
constexpr int BH = 16;       // B * H
constexpr float FSCALE = 0.125f;  // DH^-0.5

DEVI f32x4 mfma16(h16x8 a, h16x8 b, f32x4 c) {
  return __builtin_amdgcn_mfma_f32_16x16x32_f16(a, b, c, 0, 0, 0);
}

DEVI void glds16(const void* g, void* l) {
  __builtin_amdgcn_global_load_lds(
      (const __attribute__((address_space(1))) unsigned int*)g,
      (__attribute__((address_space(3))) unsigned int*)l, 16, 0, 0);
}

DEVI void tri_decode(int p, int& a, int& b) {
  a = (int)((sqrtf(8.f * p + 1.f) - 1.f) * 0.5f);
  while ((a + 1) * (a + 2) / 2 <= p) ++a;
  while (a * (a + 1) / 2 > p) --a;
  b = p - a * (a + 1) / 2;
}

// ---------------- pack kernels ----------------

__global__ __launch_bounds__(256) void k_pack_x(const float* __restrict__ x, h16* __restrict__ xh) {
  int i = (blockIdx.x * 256 + threadIdx.x) * 4;
  float4 v = *(const float4*)(x + i);
  union { h16 h[4]; uint2 u; } pk;
  pk.h[0] = (h16)v.x; pk.h[1] = (h16)v.y; pk.h[2] = (h16)v.z; pk.h[3] = (h16)v.w;
  *(uint2*)(xh + i) = pk.u;
}

struct WPtrs { const float* w[7]; };

// transpose+cast each 512x512 weight: wt[o][k] = W[k][o]
__global__ __launch_bounds__(256) void k_pack_w(WPtrs wp, h16* __restrict__ wt) {
  const float* W = wp.w[blockIdx.z];
  h16* out = wt + (size_t)blockIdx.z * DIM * DIM;
  __shared__ h16 t[64][65];
  int k0 = blockIdx.x * 64, o0 = blockIdx.y * 64;
  int c = threadIdx.x & 63, r4 = threadIdx.x >> 6;
#pragma unroll
  for (int rr = 0; rr < 64; rr += 4) {
    int r = rr + r4;
    t[r][c] = (h16)W[(size_t)(k0 + r) * DIM + o0 + c];
  }
  __syncthreads();
#pragma unroll
  for (int rr = 0; rr < 64; rr += 4) {
    int r = rr + r4;
    out[(size_t)(o0 + r) * DIM + k0 + c] = t[c][r];
  }
}

// ---------------- fused QKV projection ----------------
__global__ __launch_bounds__(256, 4) void k_proj(const h16* __restrict__ xh, const h16* __restrict__ wt,
                                                 h16* __restrict__ qkv, h16* __restrict__ vcT) {
  __shared__ h16 pool[128 * 136];
  h16* Al = pool;
  h16* Bl = pool + 128 * 64;
  int m0 = blockIdx.x * 128, o0 = blockIdx.y * 128;
  int lane = threadIdx.x & 63, wv = threadIdx.x >> 6;
  int wy = wv >> 1, wx = wv & 1;
  int srow = 32 * wv;
  int lr = lane >> 3, lc = 8 * (lane & 7);
  f32x4 acc[4][4] = {};
  for (int ks0 = 0; ks0 < DIM; ks0 += 64) {
#pragma unroll
    for (int inst = 0; inst < 4; inst++) {
      int r = srow + 8 * inst;
      glds16(xh + (size_t)(m0 + r + lr) * DIM + ks0 + lc, Al + r * 64);
      glds16(wt + (size_t)(o0 + r + lr) * DIM + ks0 + lc, Bl + r * 64);
    }
    __syncthreads();
#pragma unroll
    for (int ks = 0; ks < 2; ks++) {
      h16x8 af[4], bfv[4];
      int co = 32 * ks + 8 * (lane >> 4);
#pragma unroll
      for (int i = 0; i < 4; i++) af[i] = *(const h16x8*)(Al + (64 * wy + 16 * i + (lane & 15)) * 64 + co);
#pragma unroll
      for (int j = 0; j < 4; j++) bfv[j] = *(const h16x8*)(Bl + (64 * wx + 16 * j + (lane & 15)) * 64 + co);
#pragma unroll
      for (int i = 0; i < 4; i++)
#pragma unroll
        for (int j = 0; j < 4; j++) acc[i][j] = mfma16(af[i], bfv[j], acc[i][j]);
    }
    __syncthreads();
  }
  int widx = o0 >> 9;
  float scl = (widx == 0 || widx == 3) ? FSCALE : 1.0f;
  h16 (*Clds)[136] = (h16(*)[136])pool;
#pragma unroll
  for (int i = 0; i < 4; i++)
#pragma unroll
    for (int j = 0; j < 4; j++)
#pragma unroll
      for (int r = 0; r < 4; r++) {
        int rloc = 64 * wy + 16 * i + (lane >> 4) * 4 + r;
        int cloc = 64 * wx + 16 * j + (lane & 15);
        Clds[rloc][cloc] = (h16)(acc[i][j][r] * scl);
      }
  __syncthreads();
  int t = threadIdx.x;
  {
    int rloc = t >> 1, half = t & 1;
    int gi = m0 + rloc;
    int b = gi >> 11, n = gi & 2047;
    int og = o0 + 64 * half;
    int h = (og >> 6) & 7;
    h16* dst = qkv + (((size_t)widx * BH + b * NH + h) * NN + n) * DH;
#pragma unroll
    for (int e = 0; e < 8; e++)
      *(h16x8*)(dst + 8 * e) = *(const h16x8*)&Clds[rloc][64 * half + 8 * e];
  }
  if (widx == 5) {
    int c = t & 127, rq = t >> 7;
    int og = o0 + c;
    int h = (og >> 6) & 7, d = og & 63;
    int b = m0 >> 11, nb = (m0 & 2047) + rq * 64;
    h16* dst = vcT + ((size_t)(b * NH + h) * DH + d) * NN + nb;
#pragma unroll
    for (int g = 0; g < 8; g++) {
      h16x8 w;
#pragma unroll
      for (int e = 0; e < 8; e++) w[e] = Clds[rq * 64 + 8 * g + e][c];
      *(h16x8*)(dst + 8 * g) = w;
    }
  }
}

// ---------------- term1 & sigmoid matrices (merged, triangular tile-packed) ----------------
__global__ __launch_bounds__(256, 4) void k_termsig(const h16* __restrict__ qkv,
                                                    h16* __restrict__ term, h16* __restrict__ sig, int bh0) {
  int pidx = blockIdx.x;
  int lz = blockIdx.z, bh = bh0 + lz;
  int a, bq;
  tri_decode(pidx, a, bq);
  int lane = threadIdx.x & 63, wv = threadIdx.x >> 6;
  int wy = wv >> 1, wx = wv & 1;
  int l15 = lane & 15, q4 = lane >> 4;
  int lr = lane >> 3, lchunk = lane & 7;
  __shared__ h16 pool[128 * 136];
  h16* Al = pool;
  h16* Bl = pool + 128 * 64;
  size_t slot = ((size_t)lz * 136 + (size_t)a * (a + 1) / 2 + bq) * 16384;

  for (int ph = 0; ph < 2; ph++) {
    bool is_sig = (ph == 1);
    int rt = is_sig ? bq : a;
    int jt = is_sig ? a : bq;
    const h16* A  = qkv + ((size_t)(is_sig ? 0 : 3) * BH + bh) * NN * DH;
    const h16* Bv = qkv + ((size_t)(is_sig ? 1 : 2) * BH + bh) * NN * DH;
    h16* out = (is_sig ? sig : term) + slot;
#pragma unroll
    for (int inst = 0; inst < 4; inst++) {
      int rbase = 32 * wv + 8 * inst;
      int row = rbase + lr;
      int sc_ = (lchunk ^ (row & 7)) * 8;
      glds16(A + (size_t)(rt * 128 + row) * DH + sc_, Al + rbase * 64);
      glds16(Bv + (size_t)(jt * 128 + row) * DH + sc_, Bl + rbase * 64);
    }
    __syncthreads();
    f32x4 acc[4][4] = {};
#pragma unroll
    for (int ks = 0; ks < 2; ks++) {
      int co = 32 * ks + 8 * q4;
      h16x8 af[4], bfv[4];
#pragma unroll
      for (int i = 0; i < 4; i++) {
        int row = 64 * wy + 16 * i + l15;
        af[i] = *(const h16x8*)((const char*)Al + ((row * 128 + co * 2) ^ ((row & 7) << 4)));
      }
#pragma unroll
      for (int j = 0; j < 4; j++) {
        int row = 64 * wx + 16 * j + l15;
        bfv[j] = *(const h16x8*)((const char*)Bl + ((row * 128 + co * 2) ^ ((row & 7) << 4)));
      }
#pragma unroll
      for (int i = 0; i < 4; i++)
#pragma unroll
        for (int j = 0; j < 4; j++) acc[i][j] = mfma16(af[i], bfv[j], acc[i][j]);
    }
    __syncthreads();
    h16 (*Clds)[136] = (h16(*)[136])pool;
#pragma unroll
    for (int i = 0; i < 4; i++)
#pragma unroll
      for (int j = 0; j < 4; j++)
#pragma unroll
        for (int r = 0; r < 4; r++) {
          int rloc = 64 * wy + 16 * i + q4 * 4 + r;
          int cloc = 64 * wx + 16 * j + l15;
          int gr = rt * 128 + rloc;
          int gj = jt * 128 + cloc;
          float v = acc[i][j][r];
          float o;
          if (!is_sig) o = (gj <= gr) ? v : 0.f;
          else         o = (gj > gr) ? 1.f / (1.f + __expf(-v)) : 0.f;
          Clds[rloc][cloc] = (h16)o;
        }
    __syncthreads();
    int t = threadIdx.x;
    int rloc = t >> 1, half = t & 1;
    h16* dst = out + (size_t)rloc * 128 + 64 * half;
#pragma unroll
    for (int e = 0; e < 8; e++)
      *(h16x8*)(dst + 8 * e) = *(const h16x8*)&Clds[rloc][64 * half + 8 * e];
    __syncthreads();  // Clds fully consumed before next phase's stage overwrites pool
  }
}

// ---------------- scores + fused PV (packed term/sig, unshifted exp) ----------------
__global__ __launch_bounds__(256, 4) void k_scores(const h16* __restrict__ qkv,
                                                   const h16* __restrict__ term, const h16* __restrict__ sig,
                                                   const h16* __restrict__ vcT,
                                                   h16* __restrict__ Ot,
                                                   float* __restrict__ psum, int bh0) {
  __shared__ h16 pool[128 * 136];  // loop: Al+Bl (32KB); epilogue: Clds[128][136] (P)
  h16* Al = pool;
  h16* Bl = pool + 128 * 64;
  int nwg = gridDim.x;
  int q = nwg >> 3, rmd = nwg & 7;
  int xcd = blockIdx.x & 7, idx = blockIdx.x >> 3;
  int wg = (xcd < rmd) ? xcd * (q + 1) + idx : rmd * (q + 1) + (xcd - rmd) * q + idx;
  int lz = wg / 136, r = wg % 136;
  int It = 15, base = 0;               // descending: longest K-loops first
  while (r - base >= It + 1) { base += It + 1; --It; }
  int Kt = r - base;                   // Kt <= It
  int bh = bh0 + lz;
  int i0 = It * 128, k0 = Kt * 128;
  int triIt = It * (It + 1) / 2;
  const h16* termP = term + (size_t)lz * 136 * 16384;
  const h16* sigP  = sig + (size_t)lz * 136 * 16384;
  int lane = threadIdx.x & 63, wv = threadIdx.x >> 6;
  int wy = wv >> 1, wx = wv & 1;
  int l15 = lane & 15, q4 = lane >> 4;
  int lr = lane >> 3, lchunk = lane & 7;
  f32x4 acc[4][4] = {};
  for (int js = k0; js < i0 + 128; js += 64) {
    int jt = js >> 7, joff = js & 64;
    const h16* At = termP + (size_t)(triIt + jt) * 16384;            // term tile (It, jt)
    const h16* Bt = sigP + (size_t)(jt * (jt + 1) / 2 + Kt) * 16384; // sig tile (Kt, jt)
#pragma unroll
    for (int inst = 0; inst < 4; inst++) {
      int rbase = 32 * wv + 8 * inst;
      int row = rbase + lr;
      int sc_ = (lchunk ^ (row & 7)) * 8;
      glds16(At + (size_t)row * 128 + joff + sc_, Al + rbase * 64);
      glds16(Bt + (size_t)row * 128 + joff + sc_, Bl + rbase * 64);
    }
    __syncthreads();
#pragma unroll
    for (int ks = 0; ks < 2; ks++) {
      int co = 32 * ks + 8 * q4;
      h16x8 af[4], bfv[4];
#pragma unroll
      for (int i = 0; i < 4; i++) {
        int row = 64 * wy + 16 * i + l15;
        af[i] = *(const h16x8*)((const char*)Al + ((row * 128 + co * 2) ^ ((row & 7) << 4)));
      }
#pragma unroll
      for (int j = 0; j < 4; j++) {
        int row = 64 * wx + 16 * j + l15;
        bfv[j] = *(const h16x8*)((const char*)Bl + ((row * 128 + co * 2) ^ ((row & 7) << 4)));
      }
#pragma unroll
      for (int i = 0; i < 4; i++)
#pragma unroll
        for (int j = 0; j < 4; j++) acc[i][j] = mfma16(af[i], bfv[j], acc[i][j]);
    }
    __syncthreads();
  }
  // acc = -silu(S_u)
#pragma unroll
  for (int i = 0; i < 4; i++)
#pragma unroll
    for (int j = 0; j < 4; j++)
#pragma unroll
      for (int rr = 0; rr < 4; rr++) {
        float xv = acc[i][j][rr];
        acc[i][j][rr] = -xv / (1.f + __expf(-xv));
      }
  // acc += Qc_s . Kc^T
  const h16* Q  = qkv + ((size_t)3 * BH + bh) * NN * DH;
  const h16* Kc = qkv + ((size_t)4 * BH + bh) * NN * DH;
#pragma unroll
  for (int d2 = 0; d2 < 2; d2++) {
    int kb = 32 * d2 + 8 * q4;
    h16x8 af[4], bfv[4];
#pragma unroll
    for (int i = 0; i < 4; i++)
      af[i] = *(const h16x8*)(Q + (size_t)(i0 + 64 * wy + 16 * i + l15) * DH + kb);
#pragma unroll
    for (int j = 0; j < 4; j++)
      bfv[j] = *(const h16x8*)(Kc + (size_t)(k0 + 64 * wx + 16 * j + l15) * DH + kb);
#pragma unroll
    for (int i = 0; i < 4; i++)
#pragma unroll
      for (int j = 0; j < 4; j++) acc[i][j] = mfma16(af[i], bfv[j], acc[i][j]);
  }
  // --- P = exp(masked s); mask only needed on diagonal tiles (It==Kt) ---
  h16 (*Clds)[136] = (h16(*)[136])pool;
  if (It == Kt) {
#pragma unroll
    for (int i = 0; i < 4; i++)
#pragma unroll
      for (int j = 0; j < 4; j++)
#pragma unroll
        for (int rr = 0; rr < 4; rr++) {
          int rloc = 64 * wy + 16 * i + q4 * 4 + rr;
          int cloc = 64 * wx + 16 * j + l15;
          float pv = (cloc <= rloc) ? __expf(acc[i][j][rr]) : 0.f;
          Clds[rloc][cloc] = (h16)pv;
        }
  } else {
#pragma unroll
    for (int i = 0; i < 4; i++)
#pragma unroll
      for (int j = 0; j < 4; j++)
#pragma unroll
        for (int rr = 0; rr < 4; rr++) {
          int rloc = 64 * wy + 16 * i + q4 * 4 + rr;
          int cloc = 64 * wx + 16 * j + l15;
          Clds[rloc][cloc] = (h16)__expf(acc[i][j][rr]);
        }
  }
  __syncthreads();
  // --- row partial sums ---
  int t = threadIdx.x;
  {
    int rloc = t >> 1, half = t & 1;
    float ls = 0.f;
#pragma unroll
    for (int e = 0; e < 8; e++) {
      h16x8 v8 = *(const h16x8*)&Clds[rloc][64 * half + 8 * e];
#pragma unroll
      for (int qe = 0; qe < 8; qe++) ls += (float)v8[qe];
    }
    ls += __shfl_xor(ls, 1);
    if (half == 0) psum[((size_t)lz * 16 + Kt) * NN + i0 + rloc] = ls;
  }
  // --- fused PV: O_t = P @ Vc[Kt-tile]  (each wave: 64 rows x 32 d) ---
  const h16* VT = vcT + (size_t)bh * DH * NN;  // [d][n]
  f32x4 acc2[4][2] = {};
#pragma unroll
  for (int ks = 0; ks < 4; ks++) {
    int co = 32 * ks + 8 * q4;
    h16x8 bf2[2];
#pragma unroll
    for (int n = 0; n < 2; n++)
      bf2[n] = *(const h16x8*)(VT + (size_t)(32 * wx + 16 * n + l15) * NN + k0 + co);
#pragma unroll
    for (int m = 0; m < 4; m++) {
      h16x8 af2 = *(const h16x8*)&Clds[64 * wy + 16 * m + l15][co];
#pragma unroll
      for (int n = 0; n < 2; n++) acc2[m][n] = mfma16(af2, bf2[n], acc2[m][n]);
    }
  }
  h16* ob = Ot + ((size_t)lz * 136 + triIt + Kt) * (128 * 64);
#pragma unroll
  for (int m = 0; m < 4; m++)
#pragma unroll
    for (int n = 0; n < 2; n++)
#pragma unroll
      for (int rr = 0; rr < 4; rr++) {
        int row = 64 * wy + 16 * m + 4 * q4 + rr;
        int col = 32 * wx + 16 * n + l15;
        ob[row * 64 + col] = (h16)acc2[m][n][rr];
      }
}

// ---------------- fused merge + output projection (CH==16 path, single group/block) ----------------
__global__ __launch_bounds__(256) void k_pvout(const h16* __restrict__ Ot,
                                               const float* __restrict__ psum,
                                               const h16* __restrict__ Wt,
                                               float* __restrict__ out) {
  int m0 = blockIdx.x * 16;       // global row (b*2048 + n)
  int b = m0 >> 11;
  int i0 = m0 & 2047;
  int It = i0 >> 7;
  int ntk = It + 1, triIt = It * (It + 1) / 2;
  int rbase = i0 & 127;
  __shared__ h16 attnL[16][520];  // pad 520: 2-way-free GEMM reads
  int t = threadIdx.x;
  {
    int r = t >> 4, cseg = t & 15;
    int col0 = cseg * 32;
    int h = col0 >> 6;
    int bh = b * 8 + h;
    int coff = col0 & 63;
    const float* pl = psum + (size_t)bh * 16 * NN + i0 + r;
    float L = 0.f;
    for (int k = 0; k < ntk; k++) L += pl[(size_t)k * NN];
    float invL = 1.f / L;
    float acc[32] = {};
    const h16* obase = Ot + ((size_t)bh * 136 + triIt) * 8192 + (size_t)(rbase + r) * 64 + coff;
    for (int k = 0; k < ntk; k++) {
      const h16* ob = obase + (size_t)k * 8192;
#pragma unroll
      for (int e = 0; e < 4; e++) {
        h16x8 v = *(const h16x8*)(ob + 8 * e);
#pragma unroll
        for (int qe = 0; qe < 8; qe++) acc[8 * e + qe] += (float)v[qe];
      }
    }
#pragma unroll
    for (int e = 0; e < 4; e++) {
      h16x8 o;
#pragma unroll
      for (int qe = 0; qe < 8; qe++) o[qe] = (h16)(acc[8 * e + qe] * invL);
      *(h16x8*)&attnL[r][col0 + 8 * e] = o;
    }
  }
  __syncthreads();
  // GEMM: out[m0..m0+15][:] = attnL @ Wt^T; wave wv covers out cols wv*128..+127
  int lane = t & 63, wv = t >> 6;
  int l15 = lane & 15, q4 = lane >> 4;
  f32x4 acc2[2][4] = {};
  for (int k0 = 0; k0 < DIM; k0 += 32) {
    h16x8 af = *(const h16x8*)&attnL[l15][k0 + 8 * q4];
#pragma unroll
    for (int c = 0; c < 2; c++)
#pragma unroll
      for (int tt = 0; tt < 4; tt++) {
        h16x8 bf = *(const h16x8*)(Wt + (size_t)(wv * 128 + c * 64 + tt * 16 + l15) * DIM + k0 + 8 * q4);
        acc2[c][tt] = mfma16(af, bf, acc2[c][tt]);
      }
  }
#pragma unroll
  for (int c = 0; c < 2; c++)
#pragma unroll
    for (int tt = 0; tt < 4; tt++)
#pragma unroll
      for (int rr = 0; rr < 4; rr++)
        out[(size_t)(m0 + 4 * q4 + rr) * DIM + wv * 128 + c * 64 + tt * 16 + l15] = acc2[c][tt][rr];
}

// ---------------- fallback: merge partial O tiles -> attn (CH<16 path) ----------------
__global__ __launch_bounds__(256) void k_pvm(const h16* __restrict__ Ot,
                                             const float* __restrict__ psum,
                                             h16* __restrict__ attn, int bh0) {
  int It = blockIdx.x, lz = blockIdx.y, bh = bh0 + lz;
  int t = threadIdx.x;
  int rloc = t >> 1, dh = (t & 1) * 32;
  int i = It * 128 + rloc;
  int ntk = It + 1;
  int triIt = It * (It + 1) / 2;
  const float* pl = psum + (size_t)lz * 16 * NN + i;
  float L = 0.f;
  for (int k = 0; k < ntk; k++) L += pl[(size_t)k * NN];
  float invL = 1.f / L;
  float acc[32] = {};
  for (int k = 0; k < ntk; k++) {
    const h16* ob = Ot + ((size_t)lz * 136 + triIt + k) * (128 * 64) + (size_t)rloc * 64 + dh;
#pragma unroll
    for (int e = 0; e < 4; e++) {
      h16x8 v = *(const h16x8*)(ob + 8 * e);
#pragma unroll
      for (int qe = 0; qe < 8; qe++) acc[8 * e + qe] += (float)v[qe];
    }
  }
  int hh = bh & 7, b = bh >> 3;
  h16* dst = attn + ((size_t)b * NN + i) * DIM + hh * DH + dh;
#pragma unroll
  for (int g = 0; g < 4; g++) {
    h16x8 o;
#pragma unroll
    for (int qe = 0; qe < 8; qe++) o[qe] = (h16)(acc[g * 8 + qe] * invL);
    *(h16x8*)(dst + 8 * g) = o;
  }
}

// ---------------- fallback: output projection (fp32 out) ----------------
__global__ __launch_bounds__(256) void k_outproj(const h16* __restrict__ attn, const h16* __restrict__ Wt,
                                                 float* __restrict__ out) {
  int m0 = blockIdx.x * 64, o0 = blockIdx.y * 64;
  int lane = threadIdx.x & 63, wv = threadIdx.x >> 6;
  int kb = 8 * (lane >> 4);
  f32x4 acc[4] = {};
  const h16* ap = attn + (size_t)(m0 + 16 * wv + (lane & 15)) * DIM + kb;
  const h16* bp = Wt + (size_t)(o0 + (lane & 15)) * DIM + kb;
  for (int k0 = 0; k0 < DIM; k0 += 32) {
    h16x8 af = *(const h16x8*)(ap + k0);
#pragma unroll
    for (int t = 0; t < 4; t++) {
      h16x8 bfv = *(const h16x8*)(bp + (size_t)(16 * t) * DIM + k0);
      acc[t] = mfma16(af, bfv, acc[t]);
    }
  }
  int ri = m0 + 16 * wv + (lane >> 4) * 4;
  int c0 = o0 + (lane & 15);
#pragma unroll
  for (int t = 0; t < 4; t++)
#pragma unroll
    for (int r = 0; r < 4; r++) out[(size_t)(ri + r) * DIM + c0 + 16 * t] = acc[t][r];
}

// ---------------- launch ----------------

extern "C" void kernel_launch(void* const* d_in, const int* in_sizes, int n_in,
                              void* d_out, int out_size, void* d_ws, size_t ws_size,
                              hipStream_t stream) {
  const float* x = (const float*)d_in[0];
  WPtrs wp;
  for (int i = 0; i < 7; i++) wp.w[i] = (const float*)d_in[1 + i];

  char* p = (char*)d_ws;
  auto alloc = [&](size_t bytes) {
    void* r = (void*)p;
    p += (bytes + 255) & ~(size_t)255;
    return r;
  };
  h16* xh   = (h16*)alloc((size_t)4096 * DIM * 2);            // 4 MB
  h16* wt   = (h16*)alloc((size_t)7 * DIM * DIM * 2);         // 3.5 MB
  h16* qkv  = (h16*)alloc((size_t)6 * BH * NN * DH * 2);      // 24 MB
  h16* vcT  = (h16*)alloc((size_t)BH * DH * NN * 2);          // 4 MB
  h16* attn = (h16*)alloc((size_t)4096 * DIM * 2);            // 4 MB (fallback path only)
  size_t used = (size_t)(p - (char*)d_ws);
  size_t ts_bh = (size_t)136 * 16384 * 2;                     // 4.46 MB packed term/sig each
  size_t ot_bh = (size_t)136 * 128 * 64 * 2;                  // 2.23 MB partial-O (h16) per bh
  size_t pp_bh = (size_t)16 * NN * 4;                         // 128 KB partials per bh
  size_t avail = ws_size > used ? ws_size - used : 0;
  int CH = 16;
  while (CH > 1 && (size_t)CH * (ts_bh * 2 + ot_bh + pp_bh) > avail) CH >>= 1;
  h16* term   = (h16*)alloc((size_t)CH * ts_bh);
  h16* sig    = (h16*)alloc((size_t)CH * ts_bh);
  h16* Ot     = (h16*)alloc((size_t)CH * ot_bh);
  float* psum = (float*)alloc((size_t)CH * pp_bh);
  const h16* wout = wt + (size_t)6 * DIM * DIM;

  k_pack_x<<<dim3(2048), dim3(256), 0, stream>>>(x, xh);
  k_pack_w<<<dim3(8, 8, 7), dim3(256), 0, stream>>>(wp, wt);
  k_proj<<<dim3(32, 24), dim3(256), 0, stream>>>(xh, wt, qkv, vcT);

  if (CH == 16) {
    k_termsig<<<dim3(136, 1, 16), dim3(256), 0, stream>>>(qkv, term, sig, 0);
    k_scores<<<dim3(136 * 16), dim3(256), 0, stream>>>(qkv, term, sig, vcT, Ot, psum, 0);
    k_pvout<<<dim3(256), dim3(256), 0, stream>>>(Ot, psum, wout, (float*)d_out);
  } else {
    for (int c0 = 0; c0 < BH; c0 += CH) {
      k_termsig<<<dim3(136, 1, CH), dim3(256), 0, stream>>>(qkv, term, sig, c0);
      k_scores<<<dim3(136 * CH), dim3(256), 0, stream>>>(qkv, term, sig, vcT, Ot, psum, c0);
      k_pvm<<<dim3(16, CH), dim3(256), 0, stream>>>(Ot, psum, attn, c0);
    }
    k_outproj<<<dim3(64, 8), dim3(256), 0, stream>>>(attn, wout, (float*)d_out);
  }
}